// Round 4
// baseline (252.521 us; speedup 1.0000x reference)
//
#include <hip/hip_runtime.h>
#include <math.h>

#define BN 32
#define NPTS 2048
#define MPTS 2048
#define ITERS 5
#define LOG2E 1.44269504088896340736f
#define RPL 4                       // rows per lane
#define ROWS_BLK (64 * RPL)         // 256 rows per block
#define NGRP (NPTS / ROWS_BLK)      // 8 row-groups per batch

typedef float v2f __attribute__((ext_vector_type(2)));

// ws layout (floats):
//  [0,192)    T   : per-batch affine 2x3
//  [192,448)  acc : per-batch 8 reduction slots
//  [512, ...) pA  : per-pair float4 (kx0,kx1,ky0,ky1), static, BN*1024 float4
#define T_OFF   0
#define ACC_OFF 192
#define PA_OFF  512

__device__ __forceinline__ v2f splat(float x) { v2f r = {x, x}; return r; }

// ---------------------------------------------------------------------------
// Heavy kernel: block = 256 rows of one batch (4 rows/lane, stride 64),
// 8 waves; wave w scans M-chunk of 256 targets (128 pairs). One broadcast
// ds_read_b128 per pair feeds 4 rows  -> LDS pipe under the exp (trans) floor.
// exponent s = qpx*kx + qpy*ky - log2e*(kx^2+ky^2) - log2e*|st|^2 = -log2e*d^2
// ---------------------------------------------------------------------------
__global__ __launch_bounds__(512, 2) void icp_rows(const float* __restrict__ source,
                                                   float* __restrict__ ws) {
    __shared__ float4 pA[MPTS / 2];       // 16 KB: (kx0,kx1,ky0,ky1)
    __shared__ float4 comb[8][RPL][64];   // 32 KB: per-wave partials
    const int tid  = threadIdx.x;
    const int wave = tid >> 6;
    const int lane = tid & 63;
    const int b    = blockIdx.x >> 3;     // 8 blocks per batch
    const int grp  = blockIdx.x & 7;
    const int row0 = grp * ROWS_BLK;

    // stage the batch's target plane (1024 float4 / 512 threads)
    const float4* gA = (const float4*)(ws + PA_OFF) + b * (MPTS / 2);
    pA[tid]       = gA[tid];
    pA[tid + 512] = gA[tid + 512];

    // per-row constants (each wave computes all RPL slices; identical across waves)
    const float* T = ws + T_OFF + b * 6;
    const float r00 = T[0], r01 = T[1], tx = T[2];
    const float r10 = T[3], r11 = T[4], ty = T[5];
    float stx[RPL], sty[RPL];
    v2f qpxv[RPL], qpyv[RPL], rcv[RPL];
#pragma unroll
    for (int j = 0; j < RPL; ++j) {
        const int row = row0 + j * 64 + lane;
        const float2 sp = ((const float2*)source)[b * NPTS + row];
        const float sx = fmaf(r00, sp.x, fmaf(r01, sp.y, tx));
        const float sy = fmaf(r10, sp.x, fmaf(r11, sp.y, ty));
        stx[j] = sx; sty[j] = sy;
        qpxv[j] = splat(2.0f * LOG2E * sx);
        qpyv[j] = splat(2.0f * LOG2E * sy);
        rcv[j]  = splat(-LOG2E * fmaf(sx, sx, sy * sy));
    }
    __syncthreads();

    v2f den[RPL], ax[RPL], ay[RPL];
#pragma unroll
    for (int j = 0; j < RPL; ++j) { den[j] = splat(0.f); ax[j] = splat(0.f); ay[j] = splat(0.f); }

    const v2f mlog2e = splat(-LOG2E);
    const float4* cp = pA + (wave << 7);  // this wave's 128 pairs
    float4 c = cp[0];
#pragma unroll 2
    for (int p = 1; p < 128; ++p) {
        const float4 n = cp[p];
        const v2f kx = {c.x, c.y};
        const v2f ky = {c.z, c.w};
        v2f q = kx * kx;
        q = __builtin_elementwise_fma(ky, ky, q);   // |t|^2 per target (amortized over rows)
#pragma unroll
        for (int j = 0; j < RPL; ++j) {
            v2f t = __builtin_elementwise_fma(q, mlog2e, rcv[j]);
            t = __builtin_elementwise_fma(ky, qpyv[j], t);
            t = __builtin_elementwise_fma(kx, qpxv[j], t);
            const v2f e = {__builtin_amdgcn_exp2f(t.x), __builtin_amdgcn_exp2f(t.y)};
            den[j] += e;
            ax[j] = __builtin_elementwise_fma(e, kx, ax[j]);
            ay[j] = __builtin_elementwise_fma(e, ky, ay[j]);
        }
        c = n;
    }
    {   // last pair
        const v2f kx = {c.x, c.y};
        const v2f ky = {c.z, c.w};
        v2f q = kx * kx;
        q = __builtin_elementwise_fma(ky, ky, q);
#pragma unroll
        for (int j = 0; j < RPL; ++j) {
            v2f t = __builtin_elementwise_fma(q, mlog2e, rcv[j]);
            t = __builtin_elementwise_fma(ky, qpyv[j], t);
            t = __builtin_elementwise_fma(kx, qpxv[j], t);
            const v2f e = {__builtin_amdgcn_exp2f(t.x), __builtin_amdgcn_exp2f(t.y)};
            den[j] += e;
            ax[j] = __builtin_elementwise_fma(e, kx, ax[j]);
            ay[j] = __builtin_elementwise_fma(e, ky, ay[j]);
        }
    }

    // per-wave partials -> LDS
#pragma unroll
    for (int j = 0; j < RPL; ++j)
        comb[wave][j][lane] = make_float4(den[j].x + den[j].y,
                                          ax[j].x + ax[j].y,
                                          ay[j].x + ay[j].y, 0.f);
    __syncthreads();

    // waves 0..3 reduce slice j=wave across the 8 M-chunks, then block-reduce
    if (wave < RPL) {
        const int j = wave;
        float dsum = 0.f, xsum = 0.f, ysum = 0.f;
#pragma unroll
        for (int sw = 0; sw < 8; ++sw) {
            const float4 pp = comb[sw][j][lane];
            dsum += pp.x; xsum += pp.y; ysum += pp.z;
        }
        const float tcx = xsum / dsum;
        const float tcy = ysum / dsum;
        const float sx = stx[j], sy = sty[j];
        float v[8] = {sx, sy, tcx, tcy, sx * tcx, sx * tcy, sy * tcx, sy * tcy};
#pragma unroll
        for (int off = 32; off > 0; off >>= 1) {
#pragma unroll
            for (int k = 0; k < 8; ++k) v[k] += __shfl_xor(v[k], off, 64);
        }
        if (lane == 0) {
            float* acc = ws + ACC_OFF + b * 8;
#pragma unroll
            for (int k = 0; k < 8; ++k) atomicAdd(acc + k, v[k]);
        }
    }
}

// ---------------------------------------------------------------------------
// Tiny per-batch update: closed-form 2x2 Kabsch (polar factor), compose T,
// re-zero acc; writes output on the last iteration.
// ---------------------------------------------------------------------------
__global__ __launch_bounds__(64) void icp_update(float* __restrict__ ws,
                                                 float* __restrict__ out,
                                                 int last) {
    const int b = threadIdx.x;
    if (b >= BN) return;
    float* acc = ws + ACC_OFF + b * 8;
    const float Ssx = acc[0], Ssy = acc[1], Stcx = acc[2], Stcy = acc[3];
    const float Sxx = acc[4], Sxy = acc[5], Syx = acc[6], Syy = acc[7];
#pragma unroll
    for (int j = 0; j < 8; ++j) acc[j] = 0.f;

    const float invN = 1.0f / (float)NPTS;
    const float csx = Ssx * invN, csy = Ssy * invN;
    const float ctx = Stcx * invN, cty = Stcy * invN;
    const float Hxx = Sxx - Ssx * ctx;
    const float Hxy = Sxy - Ssx * cty;
    const float Hyx = Syx - Ssy * ctx;
    const float Hyy = Syy - Ssy * cty;
    // A = H^T ; R_delta = polar(A) = V U^T
    const float a = Hxx, bb = Hyx, cc = Hxy, d = Hyy;
    const float det = a * d - bb * cc;
    const bool refl = (det < 0.f);
    const float xr = refl ? (a - d) : (a + d);
    const float yr = refl ? (bb + cc) : (cc - bb);
    const float r = fmaxf(sqrtf(xr * xr + yr * yr), 1e-30f);
    const float R00 = xr / r, R10 = yr / r;
    const float R01 = refl ? R10 : -R10;
    const float R11 = refl ? -R00 : R00;
    const float tdx = ctx - (R00 * csx + R01 * csy);
    const float tdy = cty - (R10 * csx + R11 * csy);
    const float cD = R00, sD = R10;
    float* Tw = ws + T_OFF + b * 6;
    const float o00 = Tw[0], o01 = Tw[1], otx = Tw[2];
    const float o10 = Tw[3], o11 = Tw[4], oty = Tw[5];
    const float n00 = cD * o00 - sD * o10;
    const float n01 = cD * o01 - sD * o11;
    const float ntx = cD * otx - sD * oty + tdx;
    const float n10 = sD * o00 + cD * o10;
    const float n11 = sD * o01 + cD * o11;
    const float nty = sD * otx + cD * oty + tdy;
    Tw[0] = n00; Tw[1] = n01; Tw[2] = ntx;
    Tw[3] = n10; Tw[4] = n11; Tw[5] = nty;
    if (last) {
        out[b * 3 + 0] = atan2f(n10, n00);
        out[b * 3 + 1] = ntx;
        out[b * 3 + 2] = nty;
    }
}

// ---------------------------------------------------------------------------
// Init: T from init_transformation, acc=0, static packed target plane:
// pA[b][p] = (x_{2p}, x_{2p+1}, y_{2p}, y_{2p+1}).
// ---------------------------------------------------------------------------
__global__ __launch_bounds__(256) void icp_init(const float* __restrict__ target,
                                                const float* __restrict__ init_t,
                                                float* __restrict__ ws) {
    const int b = blockIdx.x;
    const int tid = threadIdx.x;
    if (tid == 0) {
        const float th = init_t[b * 3 + 0];
        const float c = cosf(th), s = sinf(th);
        float* Tw = ws + T_OFF + b * 6;
        Tw[0] = c;  Tw[1] = -s; Tw[2] = init_t[b * 3 + 1];
        Tw[3] = s;  Tw[4] = c;  Tw[5] = init_t[b * 3 + 2];
        float* acc = ws + ACC_OFF + b * 8;
#pragma unroll
        for (int j = 0; j < 8; ++j) acc[j] = 0.f;
    }
    float4* gA = (float4*)(ws + PA_OFF) + b * (MPTS / 2);
#pragma unroll
    for (int i = 0; i < 4; ++i) {
        const int p = (i << 8) + tid;  // pair index [0,1024)
        const float4 kk = ((const float4*)target)[b * (MPTS / 2) + p];
        // kk = (x0,y0,x1,y1) for targets 2p,2p+1
        gA[p] = make_float4(kk.x, kk.z, kk.y, kk.w);
    }
}

extern "C" void kernel_launch(void* const* d_in, const int* in_sizes, int n_in,
                              void* d_out, int out_size, void* d_ws, size_t ws_size,
                              hipStream_t stream) {
    const float* source = (const float*)d_in[0];
    const float* target = (const float*)d_in[1];
    const float* initt  = (const float*)d_in[2];
    float* out = (float*)d_out;
    float* ws  = (float*)d_ws;

    icp_init<<<BN, 256, 0, stream>>>(target, initt, ws);
    for (int it = 0; it < ITERS; ++it) {
        icp_rows<<<BN * NGRP, 512, 0, stream>>>(source, ws);
        icp_update<<<1, 64, 0, stream>>>(ws, out, it == ITERS - 1);
    }
}

// Round 6
// 210.381 us; speedup vs baseline: 1.2003x; 1.2003x over previous
//
#include <hip/hip_runtime.h>
#include <math.h>

#define BN 32
#define NPTS 2048
#define MPTS 2048
#define ITERS 5
#define NTILES 128                 // MPTS/16 target tiles per batch
#define LOG2E 1.44269504088896340736f
#define SHIFT_C 14.0f              // log2-domain headroom so P=2^(C-log2e*d^2) stays in f16

typedef _Float16 v8h __attribute__((ext_vector_type(8)));
typedef _Float16 v4h __attribute__((ext_vector_type(4)));
typedef float    v4f __attribute__((ext_vector_type(4)));

// ws layout (floats):
//  [0,192)    T   : per-batch affine 2x3
//  [192,448)  acc : per-batch 8 reduction slots
//  A1 plane @ 512:              BN*128*64 v8h (16 B each) = 4 MB  (S-MFMA A frags, static)
//  A2 plane @ 512+1048576:      BN*128*64 v4h ( 8 B each) = 2 MB  (PV-MFMA A frags, static)
#define T_OFF   0
#define ACC_OFF 192
#define A1_OFF  512
#define A2_OFF  (512 + BN * NTILES * 64 * 4)

// ---------------------------------------------------------------------------
// Heavy kernel. Block = batch b, 64-source-row group g (4 n-tiles), 4 waves;
// wave w scans m-quarter (32 target tiles). Per tile-pair:
//   D1 = mfma_16x16x32_f16(A1[m], B1[n], 0)          // scores S^T[m][n] (fp32)
//   P  = cvt_pkrtz(exp2(D1))                          // f16, D-layout == B-layout(K=16)
//   D2 = mfma_16x16x16_f16(A2[m], P, D2)              // rows: den, ax, ay
// Split-f16 slots give s to ~3e-5 abs (lo*lo dropped).
// ---------------------------------------------------------------------------
__global__ __launch_bounds__(256, 4) void icp_rows(const float* __restrict__ source,
                                                   float* __restrict__ ws) {
    const int tid = threadIdx.x;
    const int wv  = tid >> 6;
    const int l   = tid & 63;
    const int q   = l >> 4;
    const int col = l & 15;
    const int b   = blockIdx.x & 31;   // batch (mod-8 XCD-friendly)
    const int g   = blockIdx.x >> 5;   // n-group 0..31 (64 rows)

    const float* T = ws + T_OFF + b * 6;
    const float r00 = T[0], r01 = T[1], tx = T[2];
    const float r10 = T[3], r11 = T[4], ty = T[5];

    const _Float16 h0 = (_Float16)0.0f;
    const _Float16 h1 = (_Float16)1.0f;

    // Build B1 frags + keep st for the 4 n-tiles (this lane covers col l&15)
    v8h B1[4];
    float stxv[4], styv[4];
#pragma unroll
    for (int nt = 0; nt < 4; ++nt) {
        const int row = g * 64 + nt * 16 + col;
        const float2 sp = ((const float2*)source)[b * NPTS + row];
        const float sx = fmaf(r00, sp.x, fmaf(r01, sp.y, tx));
        const float sy = fmaf(r10, sp.x, fmaf(r11, sp.y, ty));
        stxv[nt] = sx; styv[nt] = sy;
        const float qpx = 2.0f * LOG2E * sx;
        const float qpy = 2.0f * LOG2E * sy;
        const float rc  = SHIFT_C - LOG2E * fmaf(sx, sx, sy * sy);
        const _Float16 qpxh = (_Float16)qpx;
        const _Float16 qpxl = (_Float16)(qpx - (float)qpxh);
        const _Float16 qpyh = (_Float16)qpy;
        const _Float16 qpyl = (_Float16)(qpy - (float)qpyh);
        const _Float16 rch  = (_Float16)rc;
        const _Float16 rcl  = (_Float16)(rc - (float)rch);
        v8h f;
        if (q == 0)      f = (v8h){qpxh, qpxl, qpxh, qpyh, qpyl, qpyh, h1, h1};
        else if (q == 1) f = (v8h){rch, rcl, h0, h0, h0, h0, h0, h0};
        else             f = (v8h){h0, h0, h0, h0, h0, h0, h0, h0};
        B1[nt] = f;
    }

    v4f D2[4];
#pragma unroll
    for (int nt = 0; nt < 4; ++nt) D2[nt] = (v4f){0.f, 0.f, 0.f, 0.f};
    const v4f zero4 = (v4f){0.f, 0.f, 0.f, 0.f};

    // m loop over this wave's 32 target tiles, prefetching A-frags from global/L2
    const v8h* A1p = (const v8h*)(ws + A1_OFF) + ((size_t)(b * NTILES + wv * 32) * 64 + l);
    const v4h* A2p = (const v4h*)(ws + A2_OFF) + ((size_t)(b * NTILES + wv * 32) * 64 + l);
    v8h a1 = A1p[0];
    v4h a2 = A2p[0];
    for (int it = 0; it < 32; ++it) {
        const int itn = (it < 31) ? (it + 1) : it;
        const v8h na1 = A1p[(size_t)itn * 64];
        const v4h na2 = A2p[(size_t)itn * 64];

        v4f D1[4];
#pragma unroll
        for (int nt = 0; nt < 4; ++nt)
            D1[nt] = __builtin_amdgcn_mfma_f32_16x16x32_f16(a1, B1[nt], zero4, 0, 0, 0);
#pragma unroll
        for (int nt = 0; nt < 4; ++nt) {
            const float e0 = __builtin_amdgcn_exp2f(D1[nt][0]);
            const float e1 = __builtin_amdgcn_exp2f(D1[nt][1]);
            const float e2 = __builtin_amdgcn_exp2f(D1[nt][2]);
            const float e3 = __builtin_amdgcn_exp2f(D1[nt][3]);
            const auto p01 = __builtin_amdgcn_cvt_pkrtz(e0, e1);  // __fp16 x2
            const auto p23 = __builtin_amdgcn_cvt_pkrtz(e2, e3);
            const v4h P = (v4h){(_Float16)p01.x, (_Float16)p01.y,
                                (_Float16)p23.x, (_Float16)p23.y};
            D2[nt] = __builtin_amdgcn_mfma_f32_16x16x16f16(a2, P, D2[nt], 0, 0, 0);
        }
        a1 = na1; a2 = na2;
    }

    // Combine the 4 m-quarter waves: D2 rows 0..2 (den, ax, ay) live in lanes 0-15
    __shared__ float4 comb[4][4][16];  // [wave][nt][col]
    if (l < 16) {
#pragma unroll
        for (int nt = 0; nt < 4; ++nt)
            comb[wv][nt][col] = make_float4(D2[nt][0], D2[nt][1], D2[nt][2], 0.f);
    }
    __syncthreads();

    // lane l handles row (g*64 + q*16 + col): sum quarters, tc = ax/den
    float den = 0.f, ax = 0.f, ay = 0.f;
#pragma unroll
    for (int w = 0; w < 4; ++w) {
        const float4 p = comb[w][q][col];
        den += p.x; ax += p.y; ay += p.z;
    }
    const float tcx = ax / den;
    const float tcy = ay / den;
    const float sx = stxv[q], sy = styv[q];
    float v[8] = {sx, sy, tcx, tcy, sx * tcx, sx * tcy, sy * tcx, sy * tcy};
#pragma unroll
    for (int off = 32; off > 0; off >>= 1) {
#pragma unroll
        for (int j = 0; j < 8; ++j) v[j] += __shfl_xor(v[j], off, 64);
    }
    if (tid == 0) {
        float* acc = ws + ACC_OFF + b * 8;
#pragma unroll
        for (int j = 0; j < 8; ++j) atomicAdd(acc + j, v[j]);
    }
}

// ---------------------------------------------------------------------------
// Tiny per-batch update: closed-form 2x2 Kabsch (polar factor), compose T,
// re-zero acc; writes output on the last iteration.
// ---------------------------------------------------------------------------
__global__ __launch_bounds__(64) void icp_update(float* __restrict__ ws,
                                                 float* __restrict__ out,
                                                 int last) {
    const int b = threadIdx.x;
    if (b >= BN) return;
    float* acc = ws + ACC_OFF + b * 8;
    const float Ssx = acc[0], Ssy = acc[1], Stcx = acc[2], Stcy = acc[3];
    const float Sxx = acc[4], Sxy = acc[5], Syx = acc[6], Syy = acc[7];
#pragma unroll
    for (int j = 0; j < 8; ++j) acc[j] = 0.f;

    const float invN = 1.0f / (float)NPTS;
    const float csx = Ssx * invN, csy = Ssy * invN;
    const float ctx = Stcx * invN, cty = Stcy * invN;
    const float Hxx = Sxx - Ssx * ctx;
    const float Hxy = Sxy - Ssx * cty;
    const float Hyx = Syx - Ssy * ctx;
    const float Hyy = Syy - Ssy * cty;
    // A = H^T ; R_delta = polar(A) = V U^T
    const float a = Hxx, bb = Hyx, cc = Hxy, d = Hyy;
    const float det = a * d - bb * cc;
    const bool refl = (det < 0.f);
    const float xr = refl ? (a - d) : (a + d);
    const float yr = refl ? (bb + cc) : (cc - bb);
    const float r = fmaxf(sqrtf(xr * xr + yr * yr), 1e-30f);
    const float R00 = xr / r, R10 = yr / r;
    const float R01 = refl ? R10 : -R10;
    const float R11 = refl ? -R00 : R00;
    const float tdx = ctx - (R00 * csx + R01 * csy);
    const float tdy = cty - (R10 * csx + R11 * csy);
    const float cD = R00, sD = R10;
    float* Tw = ws + T_OFF + b * 6;
    const float o00 = Tw[0], o01 = Tw[1], otx = Tw[2];
    const float o10 = Tw[3], o11 = Tw[4], oty = Tw[5];
    const float n00 = cD * o00 - sD * o10;
    const float n01 = cD * o01 - sD * o11;
    const float ntx = cD * otx - sD * oty + tdx;
    const float n10 = sD * o00 + cD * o10;
    const float n11 = sD * o01 + cD * o11;
    const float nty = sD * otx + cD * oty + tdy;
    Tw[0] = n00; Tw[1] = n01; Tw[2] = ntx;
    Tw[3] = n10; Tw[4] = n11; Tw[5] = nty;
    if (last) {
        out[b * 3 + 0] = atan2f(n10, n00);
        out[b * 3 + 1] = ntx;
        out[b * 3 + 2] = nty;
    }
}

// ---------------------------------------------------------------------------
// Init: T + acc, then the static A1/A2 fragment planes (targets never change).
// A1[tile][lane]: q=0 -> {kxh,kxh,kxl,kyh,kyh,kyl,bmh,bml} of m=tile*16+col;
//                 q=1 -> {1,1,0,...}; q>=2 -> 0.   (bm = -log2e*|t|^2)
// A2[tile][lane]: i=col selects W-component: i=0 -> 1; i=1 -> kx; i=2 -> ky; else 0
//                 for the 4 targets m = tile*16 + q*4 + j.
// ---------------------------------------------------------------------------
__global__ __launch_bounds__(256) void icp_init(const float* __restrict__ target,
                                                const float* __restrict__ init_t,
                                                float* __restrict__ ws) {
    const int b = blockIdx.x;
    const int tid = threadIdx.x;
    const int wv = tid >> 6;
    const int l = tid & 63;
    const int q = l >> 4;
    const int col = l & 15;
    if (tid == 0) {
        const float th = init_t[b * 3 + 0];
        const float c = cosf(th), s = sinf(th);
        float* Tw = ws + T_OFF + b * 6;
        Tw[0] = c;  Tw[1] = -s; Tw[2] = init_t[b * 3 + 1];
        Tw[3] = s;  Tw[4] = c;  Tw[5] = init_t[b * 3 + 2];
        float* acc = ws + ACC_OFF + b * 8;
#pragma unroll
        for (int j = 0; j < 8; ++j) acc[j] = 0.f;
    }
    const _Float16 h0 = (_Float16)0.0f;
    const _Float16 h1 = (_Float16)1.0f;
    v8h* A1 = (v8h*)(ws + A1_OFF) + (size_t)b * NTILES * 64;
    v4h* A2 = (v4h*)(ws + A2_OFF) + (size_t)b * NTILES * 64;
    const float2* tg = (const float2*)target + b * MPTS;

    for (int t = wv; t < NTILES; t += 4) {
        {   // A1 frag
            const float2 k = tg[t * 16 + col];
            const float bm = -LOG2E * fmaf(k.x, k.x, k.y * k.y);
            const _Float16 kxh = (_Float16)k.x;
            const _Float16 kxl = (_Float16)(k.x - (float)kxh);
            const _Float16 kyh = (_Float16)k.y;
            const _Float16 kyl = (_Float16)(k.y - (float)kyh);
            const _Float16 bmh = (_Float16)bm;
            const _Float16 bml = (_Float16)(bm - (float)bmh);
            v8h f;
            if (q == 0)      f = (v8h){kxh, kxh, kxl, kyh, kyh, kyl, bmh, bml};
            else if (q == 1) f = (v8h){h1, h1, h0, h0, h0, h0, h0, h0};
            else             f = (v8h){h0, h0, h0, h0, h0, h0, h0, h0};
            A1[t * 64 + l] = f;
        }
        {   // A2 frag
            const int m0 = t * 16 + q * 4;
            const float2 k0 = tg[m0 + 0];
            const float2 k1 = tg[m0 + 1];
            const float2 k2 = tg[m0 + 2];
            const float2 k3 = tg[m0 + 3];
            v4h f;
            if (col == 0)      f = (v4h){h1, h1, h1, h1};
            else if (col == 1) f = (v4h){(_Float16)k0.x, (_Float16)k1.x, (_Float16)k2.x, (_Float16)k3.x};
            else if (col == 2) f = (v4h){(_Float16)k0.y, (_Float16)k1.y, (_Float16)k2.y, (_Float16)k3.y};
            else               f = (v4h){h0, h0, h0, h0};
            A2[t * 64 + l] = f;
        }
    }
}

extern "C" void kernel_launch(void* const* d_in, const int* in_sizes, int n_in,
                              void* d_out, int out_size, void* d_ws, size_t ws_size,
                              hipStream_t stream) {
    const float* source = (const float*)d_in[0];
    const float* target = (const float*)d_in[1];
    const float* initt  = (const float*)d_in[2];
    float* out = (float*)d_out;
    float* ws  = (float*)d_ws;

    icp_init<<<BN, 256, 0, stream>>>(target, initt, ws);
    for (int it = 0; it < ITERS; ++it) {
        icp_rows<<<BN * 32, 256, 0, stream>>>(source, ws);
        icp_update<<<1, 64, 0, stream>>>(ws, out, it == ITERS - 1);
    }
}

// Round 7
// 202.897 us; speedup vs baseline: 1.2446x; 1.0369x over previous
//
#include <hip/hip_runtime.h>
#include <math.h>

#define BN 32
#define NPTS 2048
#define MPTS 2048
#define ITERS 5
#define NTILES 128                 // MPTS/16 target tiles per batch
#define LOG2E 1.44269504088896340736f
#define SHIFT_C 14.0f              // log2 headroom so P=2^(C-log2e*d^2) fits f16

typedef _Float16 v8h __attribute__((ext_vector_type(8)));
typedef _Float16 v4h __attribute__((ext_vector_type(4)));
typedef float    v4f __attribute__((ext_vector_type(4)));

// ws layout (floats):
//  [0,192)    T   : per-batch affine 2x3
//  [192,448)  acc : per-batch 8 reduction slots
//  P1 @ 512:  BN*2048 v8h (16 B/target)  = 1 MB   {kxh,kxh,kxl,kyh,kyh,kyl,bmh,bml}
//  P2 @ P1+BN*8192 floats: BN*512 v8h    = 256 KB {kx0..3, ky0..3} per (tile,q)
#define T_OFF   0
#define ACC_OFF 192
#define P1_OFF  512
#define P2_OFF  (512 + BN * MPTS * 4)

// ---------------------------------------------------------------------------
// Heavy kernel. Block = batch b, 64-row group g (4 n-tiles), 4 waves; wave wv
// scans m-quarter (32 tiles). Compact payloads live in LDS; each lane's MFMA
// A-operand comes from ds_read at base_lane + it*step_lane, where const/zero
// lanes point at fixed slots (step=0) -> no per-iter lane-role selects.
//   D1 = mfma_16x16x32_f16(a1, B1[nt], 0)   // scores (fp32)
//   P  = pkrtz(exp2(D1))                     // f16; D-layout == B-layout(K=16)
//   D2 = mfma_16x16x16_f16(a2, P, D2)        // rows 0..2 = den, ax, ay
// ---------------------------------------------------------------------------
__global__ __launch_bounds__(256) void icp_rows(const float* __restrict__ source,
                                                float* __restrict__ ws) {
    __shared__ v8h A1s[2080];            // 2048 payload + [2048]=const11 [2049]=zero + OOB pad
    __shared__ v8h A2s[528];             // 512 payload + [512]=ones4 [513]=zero + OOB pad
    __shared__ float4 comb[4][4][16];    // cross-wave combine
    const int tid = threadIdx.x;
    const int wv  = tid >> 6;
    const int l   = tid & 63;
    const int q   = l >> 4;
    const int col = l & 15;
    const int b   = blockIdx.x & 31;     // batch
    const int g   = blockIdx.x >> 5;     // 64-row group 0..31

    // ---- stage compact payloads (coalesced float4 copies) ----
    const float4* g1 = (const float4*)(ws + P1_OFF) + (size_t)b * 2048;
    float4* s1 = (float4*)A1s;
#pragma unroll
    for (int i = 0; i < 8; ++i) s1[tid + i * 256] = g1[tid + i * 256];
    const float4* g2 = (const float4*)(ws + P2_OFF) + (size_t)b * 512;
    float4* s2 = (float4*)A2s;
    s2[tid] = g2[tid];
    s2[tid + 256] = g2[tid + 256];

    const _Float16 h0 = (_Float16)0.0f;
    const _Float16 h1 = (_Float16)1.0f;
    if (tid == 0) {
        A1s[2048] = (v8h){h1, h1, h0, h0, h0, h0, h0, h0};
        A1s[2049] = (v8h){h0, h0, h0, h0, h0, h0, h0, h0};
        A2s[512]  = (v8h){h1, h1, h1, h1, h0, h0, h0, h0};
        A2s[513]  = (v8h){h0, h0, h0, h0, h0, h0, h0, h0};
    }

    // ---- B1 frags + st for the 4 n-tiles (overlaps staging) ----
    const float* T = ws + T_OFF + b * 6;
    const float r00 = T[0], r01 = T[1], tx = T[2];
    const float r10 = T[3], r11 = T[4], ty = T[5];
    v8h B1[4];
    float stxv[4], styv[4];
#pragma unroll
    for (int nt = 0; nt < 4; ++nt) {
        const int row = g * 64 + nt * 16 + col;
        const float2 sp = ((const float2*)source)[b * NPTS + row];
        const float sx = fmaf(r00, sp.x, fmaf(r01, sp.y, tx));
        const float sy = fmaf(r10, sp.x, fmaf(r11, sp.y, ty));
        stxv[nt] = sx; styv[nt] = sy;
        const float qpx = 2.0f * LOG2E * sx;
        const float qpy = 2.0f * LOG2E * sy;
        const float rc  = SHIFT_C - LOG2E * fmaf(sx, sx, sy * sy);
        const _Float16 qpxh = (_Float16)qpx;
        const _Float16 qpxl = (_Float16)(qpx - (float)qpxh);
        const _Float16 qpyh = (_Float16)qpy;
        const _Float16 qpyl = (_Float16)(qpy - (float)qpyh);
        const _Float16 rch  = (_Float16)rc;
        const _Float16 rcl  = (_Float16)(rc - (float)rch);
        v8h f;
        if (q == 0)      f = (v8h){qpxh, qpxl, qpxh, qpyh, qpyl, qpyh, h1, h1};
        else if (q == 1) f = (v8h){rch, rcl, h0, h0, h0, h0, h0, h0};
        else             f = (v8h){h0, h0, h0, h0, h0, h0, h0, h0};
        B1[nt] = f;
    }
    __syncthreads();

    // ---- per-lane LDS addressing: base + it*step; const lanes have step 0 ----
    const char* A1c = (const char*)A1s;
    const char* A2c = (const char*)A2s;
    int ad1 = (q == 0) ? (wv * 512 + col) * 16 : ((q == 1) ? 2048 * 16 : 2049 * 16);
    const int st1 = (q == 0) ? 256 : 0;               // next tile = +16 targets = +256 B
    int ad2 = (col == 1) ? (wv * 2048 + q * 16)
            : (col == 2) ? (wv * 2048 + q * 16 + 8)
            : ((col == 0) ? 512 * 16 : 513 * 16);
    const int st2 = (col == 1 || col == 2) ? 64 : 0;  // next tile = +4 entries = +64 B

    v4f D2[4];
#pragma unroll
    for (int nt = 0; nt < 4; ++nt) D2[nt] = (v4f){0.f, 0.f, 0.f, 0.f};
    const v4f zero4 = (v4f){0.f, 0.f, 0.f, 0.f};

    v8h a1 = *(const v8h*)(A1c + ad1);
    v4h a2 = *(const v4h*)(A2c + ad2);
    for (int it = 0; it < 32; ++it) {
        ad1 += st1; ad2 += st2;                       // last iter reads pad slots (harmless)
        const v8h n1 = *(const v8h*)(A1c + ad1);
        const v4h n2 = *(const v4h*)(A2c + ad2);

        v4f D1[4];
#pragma unroll
        for (int nt = 0; nt < 4; ++nt)
            D1[nt] = __builtin_amdgcn_mfma_f32_16x16x32_f16(a1, B1[nt], zero4, 0, 0, 0);
#pragma unroll
        for (int nt = 0; nt < 4; ++nt) {
            const float e0 = __builtin_amdgcn_exp2f(D1[nt][0]);
            const float e1 = __builtin_amdgcn_exp2f(D1[nt][1]);
            const float e2 = __builtin_amdgcn_exp2f(D1[nt][2]);
            const float e3 = __builtin_amdgcn_exp2f(D1[nt][3]);
            const auto p01 = __builtin_amdgcn_cvt_pkrtz(e0, e1);  // __fp16 x2
            const auto p23 = __builtin_amdgcn_cvt_pkrtz(e2, e3);
            const v4h P = (v4h){(_Float16)p01.x, (_Float16)p01.y,
                                (_Float16)p23.x, (_Float16)p23.y};
            D2[nt] = __builtin_amdgcn_mfma_f32_16x16x16f16(a2, P, D2[nt], 0, 0, 0);
        }
        a1 = n1; a2 = n2;
    }

    // ---- combine 4 m-quarter waves; rows 0..2 of D2 = den, ax, ay ----
    if (l < 16) {
#pragma unroll
        for (int nt = 0; nt < 4; ++nt)
            comb[wv][nt][col] = make_float4(D2[nt][0], D2[nt][1], D2[nt][2], 0.f);
    }
    __syncthreads();

    float den = 0.f, ax = 0.f, ay = 0.f;
#pragma unroll
    for (int w = 0; w < 4; ++w) {
        const float4 p = comb[w][q][col];
        den += p.x; ax += p.y; ay += p.z;
    }
    const float tcx = ax / den;
    const float tcy = ay / den;
    const float sx = stxv[q], sy = styv[q];
    float v[8] = {sx, sy, tcx, tcy, sx * tcx, sx * tcy, sy * tcx, sy * tcy};
#pragma unroll
    for (int off = 32; off > 0; off >>= 1) {
#pragma unroll
        for (int j = 0; j < 8; ++j) v[j] += __shfl_xor(v[j], off, 64);
    }
    if (tid == 0) {
        float* acc = ws + ACC_OFF + b * 8;
#pragma unroll
        for (int j = 0; j < 8; ++j) atomicAdd(acc + j, v[j]);
    }
}

// ---------------------------------------------------------------------------
// Tiny per-batch update: closed-form 2x2 Kabsch (polar factor), compose T,
// re-zero acc; writes output on the last iteration.
// ---------------------------------------------------------------------------
__global__ __launch_bounds__(64) void icp_update(float* __restrict__ ws,
                                                 float* __restrict__ out,
                                                 int last) {
    const int b = threadIdx.x;
    if (b >= BN) return;
    float* acc = ws + ACC_OFF + b * 8;
    const float Ssx = acc[0], Ssy = acc[1], Stcx = acc[2], Stcy = acc[3];
    const float Sxx = acc[4], Sxy = acc[5], Syx = acc[6], Syy = acc[7];
#pragma unroll
    for (int j = 0; j < 8; ++j) acc[j] = 0.f;

    const float invN = 1.0f / (float)NPTS;
    const float csx = Ssx * invN, csy = Ssy * invN;
    const float ctx = Stcx * invN, cty = Stcy * invN;
    const float Hxx = Sxx - Ssx * ctx;
    const float Hxy = Sxy - Ssx * cty;
    const float Hyx = Syx - Ssy * ctx;
    const float Hyy = Syy - Ssy * cty;
    // A = H^T ; R_delta = polar(A) = V U^T
    const float a = Hxx, bb = Hyx, cc = Hxy, d = Hyy;
    const float det = a * d - bb * cc;
    const bool refl = (det < 0.f);
    const float xr = refl ? (a - d) : (a + d);
    const float yr = refl ? (bb + cc) : (cc - bb);
    const float r = fmaxf(sqrtf(xr * xr + yr * yr), 1e-30f);
    const float R00 = xr / r, R10 = yr / r;
    const float R01 = refl ? R10 : -R10;
    const float R11 = refl ? -R00 : R00;
    const float tdx = ctx - (R00 * csx + R01 * csy);
    const float tdy = cty - (R10 * csx + R11 * csy);
    const float cD = R00, sD = R10;
    float* Tw = ws + T_OFF + b * 6;
    const float o00 = Tw[0], o01 = Tw[1], otx = Tw[2];
    const float o10 = Tw[3], o11 = Tw[4], oty = Tw[5];
    const float n00 = cD * o00 - sD * o10;
    const float n01 = cD * o01 - sD * o11;
    const float ntx = cD * otx - sD * oty + tdx;
    const float n10 = sD * o00 + cD * o10;
    const float n11 = sD * o01 + cD * o11;
    const float nty = sD * otx + cD * oty + tdy;
    Tw[0] = n00; Tw[1] = n01; Tw[2] = ntx;
    Tw[3] = n10; Tw[4] = n11; Tw[5] = nty;
    if (last) {
        out[b * 3 + 0] = atan2f(n10, n00);
        out[b * 3 + 1] = ntx;
        out[b * 3 + 2] = nty;
    }
}

// ---------------------------------------------------------------------------
// Init: T + acc, then compact static payload planes.
// P1[b][m]           = {kxh,kxh,kxl,kyh,kyh,kyl,bmh,bml}   (bm = -log2e*|t|^2)
// P2[b][tile*4+q]    = {kx[4m0..+3] as f16, ky[...] as f16}, m0 = 4*(tile*4+q)
// ---------------------------------------------------------------------------
__global__ __launch_bounds__(256) void icp_init(const float* __restrict__ target,
                                                const float* __restrict__ init_t,
                                                float* __restrict__ ws) {
    const int b = blockIdx.x;
    const int tid = threadIdx.x;
    if (tid == 0) {
        const float th = init_t[b * 3 + 0];
        const float c = cosf(th), s = sinf(th);
        float* Tw = ws + T_OFF + b * 6;
        Tw[0] = c;  Tw[1] = -s; Tw[2] = init_t[b * 3 + 1];
        Tw[3] = s;  Tw[4] = c;  Tw[5] = init_t[b * 3 + 2];
        float* acc = ws + ACC_OFF + b * 8;
#pragma unroll
        for (int j = 0; j < 8; ++j) acc[j] = 0.f;
    }
    const float2* tg = (const float2*)target + b * MPTS;
    v8h* P1 = (v8h*)(ws + P1_OFF) + (size_t)b * MPTS;
#pragma unroll
    for (int i = 0; i < 8; ++i) {
        const int m = tid + i * 256;
        const float2 k = tg[m];
        const float bm = -LOG2E * fmaf(k.x, k.x, k.y * k.y);
        const _Float16 kxh = (_Float16)k.x;
        const _Float16 kxl = (_Float16)(k.x - (float)kxh);
        const _Float16 kyh = (_Float16)k.y;
        const _Float16 kyl = (_Float16)(k.y - (float)kyh);
        const _Float16 bmh = (_Float16)bm;
        const _Float16 bml = (_Float16)(bm - (float)bmh);
        P1[m] = (v8h){kxh, kxh, kxl, kyh, kyh, kyl, bmh, bml};
    }
    v8h* P2 = (v8h*)(ws + P2_OFF) + (size_t)b * 512;
#pragma unroll
    for (int i = 0; i < 2; ++i) {
        const int e = tid + i * 256;   // entry = tile*4+q
        const int m0 = e * 4;
        const float2 k0 = tg[m0 + 0];
        const float2 k1 = tg[m0 + 1];
        const float2 k2 = tg[m0 + 2];
        const float2 k3 = tg[m0 + 3];
        P2[e] = (v8h){(_Float16)k0.x, (_Float16)k1.x, (_Float16)k2.x, (_Float16)k3.x,
                      (_Float16)k0.y, (_Float16)k1.y, (_Float16)k2.y, (_Float16)k3.y};
    }
}

extern "C" void kernel_launch(void* const* d_in, const int* in_sizes, int n_in,
                              void* d_out, int out_size, void* d_ws, size_t ws_size,
                              hipStream_t stream) {
    const float* source = (const float*)d_in[0];
    const float* target = (const float*)d_in[1];
    const float* initt  = (const float*)d_in[2];
    float* out = (float*)d_out;
    float* ws  = (float*)d_ws;

    icp_init<<<BN, 256, 0, stream>>>(target, initt, ws);
    for (int it = 0; it < ITERS; ++it) {
        icp_rows<<<BN * 32, 256, 0, stream>>>(source, ws);
        icp_update<<<1, 64, 0, stream>>>(ws, out, it == ITERS - 1);
    }
}

// Round 8
// 193.621 us; speedup vs baseline: 1.3042x; 1.0479x over previous
//
#include <hip/hip_runtime.h>
#include <math.h>

#define BN 32
#define NPTS 2048
#define MPTS 2048
#define ITERS 5
#define LOG2E 1.44269504088896340736f
#define SHIFT_C 14.0f              // log2 headroom so P=2^(C-log2e*d^2) fits f16

typedef _Float16 v8h __attribute__((ext_vector_type(8)));
typedef _Float16 v4h __attribute__((ext_vector_type(4)));
typedef __fp16   f16x2 __attribute__((ext_vector_type(2)));
typedef float    v4f __attribute__((ext_vector_type(4)));

// ws layout (floats):
//  [0,192)    T   : per-batch affine 2x3
//  [192,448)  acc : per-batch 8 reduction slots
//  P1 @ 512:  BN*2048 v8h (16 B/target)  = 1 MB   {kxh,kxh,kxl,kyh,kyh,kyl,bmh,bml}
//  P2 @ P1+BN*8192 floats: BN*512 v8h    = 256 KB {kx0..3, ky0..3} per (tile,q)
#define T_OFF   0
#define ACC_OFF 192
#define P1_OFF  512
#define P2_OFF  (512 + BN * MPTS * 4)

// ---------------------------------------------------------------------------
// Heavy kernel. Block = batch b, 128 rows (two 64-row groups; waves 0-3 take
// group A, 4-7 group B), wave (wv&3) scans an m-quarter (32 tiles).
// Software-pipelined: D1 MFMAs for tile t+1 issue before tile t's exps,
// ds_reads prefetch at distance 2 -> MFMA->VALU latency hidden in exp stream.
//   D1 = mfma_16x16x32_f16(a1, B1[nt], 0)   // scores (fp32)
//   P  = pkrtz(exp2(D1))                     // f16; D-layout == B-layout(K=16)
//   D2 = mfma_16x16x16_f16(a2, P, D2)        // rows 0..2 = den, ax, ay
// ---------------------------------------------------------------------------
__global__ __launch_bounds__(512, 4) void icp_rows(const float* __restrict__ source,
                                                   float* __restrict__ ws) {
    __shared__ v8h A1s[2100];            // 2048 payload + const/zero slots + prefetch pad
    __shared__ v8h A2s[528];             // 512 payload + const/zero slots + pad
    __shared__ float4 comb[8][4][16];
    const int tid = threadIdx.x;
    const int wv  = tid >> 6;
    const int l   = tid & 63;
    const int q   = l >> 4;
    const int col = l & 15;
    const int wq   = wv & 3;             // m-quarter
    const int half = wv >> 2;            // row-group within block
    const int b    = blockIdx.x & 31;    // batch
    const int gg   = blockIdx.x >> 5;    // 128-row group 0..15
    const int g    = gg * 2 + half;      // 64-row group 0..31

    // ---- stage compact payloads (coalesced float4 copies) ----
    const float4* g1 = (const float4*)(ws + P1_OFF) + (size_t)b * 2048;
    float4* s1 = (float4*)A1s;
#pragma unroll
    for (int i = 0; i < 4; ++i) s1[tid + i * 512] = g1[tid + i * 512];
    const float4* g2 = (const float4*)(ws + P2_OFF) + (size_t)b * 512;
    ((float4*)A2s)[tid] = g2[tid];

    const _Float16 h0 = (_Float16)0.0f;
    const _Float16 h1 = (_Float16)1.0f;
    if (tid == 0) {
        A1s[2048] = (v8h){h1, h1, h0, h0, h0, h0, h0, h0};
        A1s[2049] = (v8h){h0, h0, h0, h0, h0, h0, h0, h0};
        A2s[512]  = (v8h){h1, h1, h1, h1, h0, h0, h0, h0};
        A2s[513]  = (v8h){h0, h0, h0, h0, h0, h0, h0, h0};
    }

    // ---- B1 frags for this wave's 4 n-tiles (rows g*64 + nt*16 + col) ----
    const float* T = ws + T_OFF + b * 6;
    const float r00 = T[0], r01 = T[1], tx = T[2];
    const float r10 = T[3], r11 = T[4], ty = T[5];
    v8h B1[4];
#pragma unroll
    for (int nt = 0; nt < 4; ++nt) {
        const int row = g * 64 + nt * 16 + col;
        const float2 sp = ((const float2*)source)[b * NPTS + row];
        const float sx = fmaf(r00, sp.x, fmaf(r01, sp.y, tx));
        const float sy = fmaf(r10, sp.x, fmaf(r11, sp.y, ty));
        const float qpx = 2.0f * LOG2E * sx;
        const float qpy = 2.0f * LOG2E * sy;
        const float rc  = SHIFT_C - LOG2E * fmaf(sx, sx, sy * sy);
        const _Float16 qpxh = (_Float16)qpx;
        const _Float16 qpxl = (_Float16)(qpx - (float)qpxh);
        const _Float16 qpyh = (_Float16)qpy;
        const _Float16 qpyl = (_Float16)(qpy - (float)qpyh);
        const _Float16 rch  = (_Float16)rc;
        const _Float16 rcl  = (_Float16)(rc - (float)rch);
        v8h f;
        if (q == 0)      f = (v8h){qpxh, qpxl, qpxh, qpyh, qpyl, qpyh, h1, h1};
        else if (q == 1) f = (v8h){rch, rcl, h0, h0, h0, h0, h0, h0};
        else             f = (v8h){h0, h0, h0, h0, h0, h0, h0, h0};
        B1[nt] = f;
    }
    __syncthreads();

    // ---- per-lane LDS addressing: base + it*step; const lanes step 0 ----
    const char* A1c = (const char*)A1s;
    const char* A2c = (const char*)A2s;
    int ad1 = (q == 0) ? (wq * 512 + col) * 16 : ((q == 1) ? 2048 * 16 : 2049 * 16);
    const int st1 = (q == 0) ? 256 : 0;
    int ad2 = (col == 1) ? (wq * 2048 + q * 16)
            : (col == 2) ? (wq * 2048 + q * 16 + 8)
            : ((col == 0) ? 512 * 16 : 513 * 16);
    const int st2 = (col == 1 || col == 2) ? 64 : 0;

    v4f D2[4];
#pragma unroll
    for (int nt = 0; nt < 4; ++nt) D2[nt] = (v4f){0.f, 0.f, 0.f, 0.f};
    const v4f zero4 = (v4f){0.f, 0.f, 0.f, 0.f};

    // ---- pipelined prologue: t0 loaded+scored, t1 loaded, t2 in flight ----
    v8h a1b = *(const v8h*)(A1c + ad1);            // t0
    v4h a2c = *(const v4h*)(A2c + ad2);
    ad1 += st1; ad2 += st2;
    v8h n1 = *(const v8h*)(A1c + ad1);             // t1 (in flight; waited at first use)
    v4h n2 = *(const v4h*)(A2c + ad2);
    v4f D1c[4];
#pragma unroll
    for (int nt = 0; nt < 4; ++nt)
        D1c[nt] = __builtin_amdgcn_mfma_f32_16x16x32_f16(a1b, B1[nt], zero4, 0, 0, 0);

    for (int it = 0; it < 32; ++it) {
        // issue loads for t+2
        ad1 += st1; ad2 += st2;
        const v8h f1 = *(const v8h*)(A1c + ad1);   // last iters read pad (harmless)
        const v4h f2 = *(const v4h*)(A2c + ad2);
        // score tile t+1 ahead of consuming tile t
        v4f D1n[4];
#pragma unroll
        for (int nt = 0; nt < 4; ++nt)
            D1n[nt] = __builtin_amdgcn_mfma_f32_16x16x32_f16(n1, B1[nt], zero4, 0, 0, 0);
        // consume tile t: exp -> pack -> accumulate
#pragma unroll
        for (int nt = 0; nt < 4; ++nt) {
            const float e0 = __builtin_amdgcn_exp2f(D1c[nt][0]);
            const float e1 = __builtin_amdgcn_exp2f(D1c[nt][1]);
            const float e2 = __builtin_amdgcn_exp2f(D1c[nt][2]);
            const float e3 = __builtin_amdgcn_exp2f(D1c[nt][3]);
            union { v4h v; f16x2 h[2]; } u;
            u.h[0] = __builtin_amdgcn_cvt_pkrtz(e0, e1);
            u.h[1] = __builtin_amdgcn_cvt_pkrtz(e2, e3);
            D2[nt] = __builtin_amdgcn_mfma_f32_16x16x16f16(a2c, u.v, D2[nt], 0, 0, 0);
        }
#pragma unroll
        for (int nt = 0; nt < 4; ++nt) D1c[nt] = D1n[nt];
        n1 = f1; a2c = n2; n2 = f2;
    }

    // ---- combine m-quarters within each row-group ----
    if (l < 16) {
#pragma unroll
        for (int nt = 0; nt < 4; ++nt)
            comb[wv][nt][col] = make_float4(D2[nt][0], D2[nt][1], D2[nt][2], 0.f);
    }
    __syncthreads();

    const int wbase = half * 4;
    float den = 0.f, ax = 0.f, ay = 0.f;
#pragma unroll
    for (int w = 0; w < 4; ++w) {
        const float4 p = comb[wbase + w][q][col];
        den += p.x; ax += p.y; ay += p.z;
    }
    const float tcx = ax / den;
    const float tcy = ay / den;
    // recompute st for this thread's row (saves 8 VGPRs through the loop)
    const int erow = g * 64 + q * 16 + col;
    const float2 sp = ((const float2*)source)[b * NPTS + erow];
    const float sx = fmaf(r00, sp.x, fmaf(r01, sp.y, tx));
    const float sy = fmaf(r10, sp.x, fmaf(r11, sp.y, ty));
    float v[8] = {sx, sy, tcx, tcy, sx * tcx, sx * tcy, sy * tcx, sy * tcy};
#pragma unroll
    for (int off = 32; off > 0; off >>= 1) {
#pragma unroll
        for (int j = 0; j < 8; ++j) v[j] += __shfl_xor(v[j], off, 64);
    }
    if (l == 0 && wq == 0) {   // one adder per row-group
        float* acc = ws + ACC_OFF + b * 8;
#pragma unroll
        for (int j = 0; j < 8; ++j) atomicAdd(acc + j, v[j]);
    }
}

// ---------------------------------------------------------------------------
// Tiny per-batch update: closed-form 2x2 Kabsch (polar factor), compose T,
// re-zero acc; writes output on the last iteration.
// ---------------------------------------------------------------------------
__global__ __launch_bounds__(64) void icp_update(float* __restrict__ ws,
                                                 float* __restrict__ out,
                                                 int last) {
    const int b = threadIdx.x;
    if (b >= BN) return;
    float* acc = ws + ACC_OFF + b * 8;
    const float Ssx = acc[0], Ssy = acc[1], Stcx = acc[2], Stcy = acc[3];
    const float Sxx = acc[4], Sxy = acc[5], Syx = acc[6], Syy = acc[7];
#pragma unroll
    for (int j = 0; j < 8; ++j) acc[j] = 0.f;

    const float invN = 1.0f / (float)NPTS;
    const float csx = Ssx * invN, csy = Ssy * invN;
    const float ctx = Stcx * invN, cty = Stcy * invN;
    const float Hxx = Sxx - Ssx * ctx;
    const float Hxy = Sxy - Ssx * cty;
    const float Hyx = Syx - Ssy * ctx;
    const float Hyy = Syy - Ssy * cty;
    // A = H^T ; R_delta = polar(A) = V U^T
    const float a = Hxx, bb = Hyx, cc = Hxy, d = Hyy;
    const float det = a * d - bb * cc;
    const bool refl = (det < 0.f);
    const float xr = refl ? (a - d) : (a + d);
    const float yr = refl ? (bb + cc) : (cc - bb);
    const float r = fmaxf(sqrtf(xr * xr + yr * yr), 1e-30f);
    const float R00 = xr / r, R10 = yr / r;
    const float R01 = refl ? R10 : -R10;
    const float R11 = refl ? -R00 : R00;
    const float tdx = ctx - (R00 * csx + R01 * csy);
    const float tdy = cty - (R10 * csx + R11 * csy);
    const float cD = R00, sD = R10;
    float* Tw = ws + T_OFF + b * 6;
    const float o00 = Tw[0], o01 = Tw[1], otx = Tw[2];
    const float o10 = Tw[3], o11 = Tw[4], oty = Tw[5];
    const float n00 = cD * o00 - sD * o10;
    const float n01 = cD * o01 - sD * o11;
    const float ntx = cD * otx - sD * oty + tdx;
    const float n10 = sD * o00 + cD * o10;
    const float n11 = sD * o01 + cD * o11;
    const float nty = sD * otx + cD * oty + tdy;
    Tw[0] = n00; Tw[1] = n01; Tw[2] = ntx;
    Tw[3] = n10; Tw[4] = n11; Tw[5] = nty;
    if (last) {
        out[b * 3 + 0] = atan2f(n10, n00);
        out[b * 3 + 1] = ntx;
        out[b * 3 + 2] = nty;
    }
}

// ---------------------------------------------------------------------------
// Init: T + acc, then compact static payload planes.
// P1[b][m]        = {kxh,kxh,kxl,kyh,kyh,kyl,bmh,bml}   (bm = -log2e*|t|^2)
// P2[b][tile*4+q] = {kx[m0..m0+3] f16, ky[...] f16}, m0 = 4*(tile*4+q)
// ---------------------------------------------------------------------------
__global__ __launch_bounds__(256) void icp_init(const float* __restrict__ target,
                                                const float* __restrict__ init_t,
                                                float* __restrict__ ws) {
    const int b = blockIdx.x;
    const int tid = threadIdx.x;
    if (tid == 0) {
        const float th = init_t[b * 3 + 0];
        const float c = cosf(th), s = sinf(th);
        float* Tw = ws + T_OFF + b * 6;
        Tw[0] = c;  Tw[1] = -s; Tw[2] = init_t[b * 3 + 1];
        Tw[3] = s;  Tw[4] = c;  Tw[5] = init_t[b * 3 + 2];
        float* acc = ws + ACC_OFF + b * 8;
#pragma unroll
        for (int j = 0; j < 8; ++j) acc[j] = 0.f;
    }
    const float2* tg = (const float2*)target + b * MPTS;
    v8h* P1 = (v8h*)(ws + P1_OFF) + (size_t)b * MPTS;
#pragma unroll
    for (int i = 0; i < 8; ++i) {
        const int m = tid + i * 256;
        const float2 k = tg[m];
        const float bm = -LOG2E * fmaf(k.x, k.x, k.y * k.y);
        const _Float16 kxh = (_Float16)k.x;
        const _Float16 kxl = (_Float16)(k.x - (float)kxh);
        const _Float16 kyh = (_Float16)k.y;
        const _Float16 kyl = (_Float16)(k.y - (float)kyh);
        const _Float16 bmh = (_Float16)bm;
        const _Float16 bml = (_Float16)(bm - (float)bmh);
        P1[m] = (v8h){kxh, kxh, kxl, kyh, kyh, kyl, bmh, bml};
    }
    v8h* P2 = (v8h*)(ws + P2_OFF) + (size_t)b * 512;
#pragma unroll
    for (int i = 0; i < 2; ++i) {
        const int e = tid + i * 256;   // entry = tile*4+q
        const int m0 = e * 4;
        const float2 k0 = tg[m0 + 0];
        const float2 k1 = tg[m0 + 1];
        const float2 k2 = tg[m0 + 2];
        const float2 k3 = tg[m0 + 3];
        P2[e] = (v8h){(_Float16)k0.x, (_Float16)k1.x, (_Float16)k2.x, (_Float16)k3.x,
                      (_Float16)k0.y, (_Float16)k1.y, (_Float16)k2.y, (_Float16)k3.y};
    }
}

extern "C" void kernel_launch(void* const* d_in, const int* in_sizes, int n_in,
                              void* d_out, int out_size, void* d_ws, size_t ws_size,
                              hipStream_t stream) {
    const float* source = (const float*)d_in[0];
    const float* target = (const float*)d_in[1];
    const float* initt  = (const float*)d_in[2];
    float* out = (float*)d_out;
    float* ws  = (float*)d_ws;

    icp_init<<<BN, 256, 0, stream>>>(target, initt, ws);
    for (int it = 0; it < ITERS; ++it) {
        icp_rows<<<BN * 16, 512, 0, stream>>>(source, ws);
        icp_update<<<1, 64, 0, stream>>>(ws, out, it == ITERS - 1);
    }
}